// Round 1
// baseline (1711.838 us; speedup 1.0000x reference)
//
#include <hip/hip_runtime.h>
#include <hip/hip_bf16.h>
#include <float.h>

#define NN 50000
#define EE 800000
#define GG 50
#define HH 4
#define DD 64
#define HD 256
#define NODE_IN 26
#define NEG_SLOPE 0.2f

// ---------------------------------------------------------------------------
// embed: h0[n] = concat(W_emb[seq[n]], node_s[n])  -> [N, 26]
// ---------------------------------------------------------------------------
__global__ void embed_kernel(const int* __restrict__ seq,
                             const float* __restrict__ node_s,
                             const float* __restrict__ W_emb,
                             float* __restrict__ h0, int n_total) {
    int idx = blockIdx.x * blockDim.x + threadIdx.x;
    if (idx >= n_total) return;
    int n = idx / NODE_IN;
    int j = idx - n * NODE_IN;
    float v;
    if (j < 20) v = W_emb[seq[n] * 20 + j];
    else        v = node_s[n * 6 + (j - 20)];
    h0[idx] = v;
}

// ---------------------------------------------------------------------------
// Tiled fp32 GEMM: C[M,N] = A[M,K] @ B[K,N] (+bias, optional relu)
// 64x64 tile, 256 threads, 4x4 per thread, K-tile 16.
// ---------------------------------------------------------------------------
__global__ __launch_bounds__(256) void gemm_kernel(
    const float* __restrict__ A, const float* __restrict__ B,
    float* __restrict__ C, const float* __restrict__ bias,
    int M, int N, int K, int relu_out) {
    __shared__ float As[16][68];   // [k][row], padded: write banks 2-way, read 2-way
    __shared__ float Bs[16][64];   // [k][col]

    int tid = threadIdx.x;
    int tx = tid & 15;             // 16 col-groups
    int ty = tid >> 4;             // 16 row-groups
    int bn = blockIdx.x * 64;
    int bm = blockIdx.y * 64;

    float acc[4][4] = {};

    for (int k0 = 0; k0 < K; k0 += 16) {
        // load A tile 64 rows x 16 k
        #pragma unroll
        for (int l = tid; l < 64 * 16; l += 256) {
            int r = l >> 4, c = l & 15;
            int gr = bm + r, gc = k0 + c;
            float v = 0.f;
            if (gr < M && gc < K) v = A[(size_t)gr * K + gc];
            As[c][r] = v;
        }
        // load B tile 16 k x 64 cols
        #pragma unroll
        for (int l = tid; l < 16 * 64; l += 256) {
            int r = l >> 6, c = l & 63;
            int gr = k0 + r;
            float v = 0.f;
            if (gr < K) v = B[(size_t)gr * N + bn + c];
            Bs[r][c] = v;
        }
        __syncthreads();
        #pragma unroll
        for (int k = 0; k < 16; ++k) {
            float4 a = *(const float4*)&As[k][ty * 4];
            float4 b = *(const float4*)&Bs[k][tx * 4];
            float av[4] = {a.x, a.y, a.z, a.w};
            float bv[4] = {b.x, b.y, b.z, b.w};
            #pragma unroll
            for (int i = 0; i < 4; ++i)
                #pragma unroll
                for (int j = 0; j < 4; ++j)
                    acc[i][j] = fmaf(av[i], bv[j], acc[i][j]);
        }
        __syncthreads();
    }

    #pragma unroll
    for (int i = 0; i < 4; ++i) {
        int row = bm + ty * 4 + i;
        if (row >= M) continue;
        #pragma unroll
        for (int j = 0; j < 4; ++j) {
            int col = bn + tx * 4 + j;
            float v = acc[i][j];
            if (bias) v += bias[col];
            if (relu_out) v = fmaxf(v, 0.f);
            C[(size_t)row * N + col] = v;
        }
    }
}

// ---------------------------------------------------------------------------
// scores: el[n,h] = sum_d ft[n,h,d]*al[h,d]; er likewise. One wave per node.
// ---------------------------------------------------------------------------
__global__ __launch_bounds__(256) void scores_kernel(
    const float* __restrict__ ft, const float* __restrict__ al,
    const float* __restrict__ ar, float* __restrict__ el,
    float* __restrict__ er) {
    int wave = (blockIdx.x * blockDim.x + threadIdx.x) >> 6;
    int lane = threadIdx.x & 63;
    if (wave >= NN) return;
    const float* row = ft + (size_t)wave * HD;
    float accl[HH], accr[HH];
    #pragma unroll
    for (int h = 0; h < HH; ++h) {
        float v = row[h * DD + lane];
        accl[h] = v * al[h * DD + lane];
        accr[h] = v * ar[h * DD + lane];
    }
    #pragma unroll
    for (int off = 32; off; off >>= 1) {
        #pragma unroll
        for (int h = 0; h < HH; ++h) {
            accl[h] += __shfl_xor(accl[h], off);
            accr[h] += __shfl_xor(accr[h], off);
        }
    }
    if (lane == 0) {
        #pragma unroll
        for (int h = 0; h < HH; ++h) {
            el[wave * HH + h] = accl[h];
            er[wave * HH + h] = accr[h];
        }
    }
}

// ---------------------------------------------------------------------------
// CSR build: histogram over dst -> scan -> scatter src per slot
// ---------------------------------------------------------------------------
__global__ void hist_kernel(const int* __restrict__ dst, int* __restrict__ cnt) {
    for (int i = blockIdx.x * blockDim.x + threadIdx.x; i < EE;
         i += gridDim.x * blockDim.x)
        atomicAdd(&cnt[dst[i]], 1);
}

__global__ __launch_bounds__(1024) void scan_kernel(
    const int* __restrict__ cnt, int* __restrict__ rowptr) {
    __shared__ int part[1024];
    int t = threadIdx.x;
    const int per = (NN + 1023) / 1024;   // 49
    int start = t * per;
    int end = start + per; if (end > NN) end = NN;
    int s = 0;
    for (int i = start; i < end; ++i) s += cnt[i];
    part[t] = s;
    __syncthreads();
    for (int off = 1; off < 1024; off <<= 1) {
        int v = (t >= off) ? part[t - off] : 0;
        __syncthreads();
        part[t] += v;
        __syncthreads();
    }
    int run = (t == 0) ? 0 : part[t - 1];
    for (int i = start; i < end; ++i) { rowptr[i] = run; run += cnt[i]; }
    if (t == 1023) rowptr[NN] = part[1023];
}

__global__ void scatter_kernel(const int* __restrict__ src,
                               const int* __restrict__ dst,
                               const int* __restrict__ rowptr,
                               int* __restrict__ fill,
                               int* __restrict__ colsrc) {
    for (int i = blockIdx.x * blockDim.x + threadIdx.x; i < EE;
         i += gridDim.x * blockDim.x) {
        int d = dst[i];
        int pos = atomicAdd(&fill[d], 1);
        colsrc[rowptr[d] + pos] = src[i];
    }
}

// ---------------------------------------------------------------------------
// aggregate: per-dst-node edge softmax + message aggregation. One wave/node.
//   pass1 max, pass2 sum(exp), pass3 accumulate alpha*ft[src]. +bias, opt relu.
// ---------------------------------------------------------------------------
__global__ __launch_bounds__(256) void aggregate_kernel(
    const float* __restrict__ ft, const float* __restrict__ el,
    const float* __restrict__ er, const int* __restrict__ rowptr,
    const int* __restrict__ colsrc, const float* __restrict__ bias,
    float* __restrict__ out, int relu_out) {
    int v = (blockIdx.x * blockDim.x + threadIdx.x) >> 6;
    int lane = threadIdx.x & 63;
    if (v >= NN) return;
    int base = rowptr[v];
    int deg = rowptr[v + 1] - base;

    float erv[HH];
    #pragma unroll
    for (int h = 0; h < HH; ++h) erv[h] = er[v * HH + h];

    // pass 1: per-head max over edges (lane-strided)
    float m[HH];
    #pragma unroll
    for (int h = 0; h < HH; ++h) m[h] = -FLT_MAX;
    for (int j = lane; j < deg; j += 64) {
        int s = colsrc[base + j];
        #pragma unroll
        for (int h = 0; h < HH; ++h) {
            float e = el[s * HH + h] + erv[h];
            e = (e >= 0.f) ? e : NEG_SLOPE * e;
            m[h] = fmaxf(m[h], e);
        }
    }
    #pragma unroll
    for (int off = 32; off; off >>= 1)
        #pragma unroll
        for (int h = 0; h < HH; ++h)
            m[h] = fmaxf(m[h], __shfl_xor(m[h], off));

    // pass 2: z = sum exp(e - m)
    float z[HH] = {0.f, 0.f, 0.f, 0.f};
    for (int j = lane; j < deg; j += 64) {
        int s = colsrc[base + j];
        #pragma unroll
        for (int h = 0; h < HH; ++h) {
            float e = el[s * HH + h] + erv[h];
            e = (e >= 0.f) ? e : NEG_SLOPE * e;
            z[h] += expf(e - m[h]);
        }
    }
    #pragma unroll
    for (int off = 32; off; off >>= 1)
        #pragma unroll
        for (int h = 0; h < HH; ++h)
            z[h] += __shfl_xor(z[h], off);
    float zinv[HH];
    #pragma unroll
    for (int h = 0; h < HH; ++h) zinv[h] = 1.f / z[h];

    // pass 3: all lanes walk all edges; lane = feature d
    float acc[HH] = {0.f, 0.f, 0.f, 0.f};
    for (int j = 0; j < deg; ++j) {
        int s = colsrc[base + j];
        float alpha[HH];
        #pragma unroll
        for (int h = 0; h < HH; ++h) {
            float e = el[s * HH + h] + erv[h];
            e = (e >= 0.f) ? e : NEG_SLOPE * e;
            alpha[h] = expf(e - m[h]) * zinv[h];
        }
        const float* fr = ft + (size_t)s * HD;
        #pragma unroll
        for (int h = 0; h < HH; ++h)
            acc[h] = fmaf(alpha[h], fr[h * DD + lane], acc[h]);
    }
    #pragma unroll
    for (int h = 0; h < HH; ++h) {
        float o = acc[h] + bias[h * DD + lane];
        if (relu_out) o = fmaxf(o, 0.f);
        out[(size_t)v * HD + h * DD + lane] = o;
    }
}

// ---------------------------------------------------------------------------
// final: out[n] = hidden[n,:512] . Wd2 + bd2 + 0.5 ; graph pooling atomics
// ---------------------------------------------------------------------------
__global__ __launch_bounds__(256) void final_kernel(
    const float* __restrict__ hidden, const float* __restrict__ Wd2,
    const float* __restrict__ bd2, const int* __restrict__ graph_id,
    float* __restrict__ out, float* __restrict__ gsum,
    float* __restrict__ gcnt) {
    int n = (blockIdx.x * blockDim.x + threadIdx.x) >> 6;
    int lane = threadIdx.x & 63;
    if (n >= NN) return;
    const float* hr = hidden + (size_t)n * 512;
    float s = 0.f;
    #pragma unroll
    for (int i = 0; i < 8; ++i)
        s = fmaf(hr[i * 64 + lane], Wd2[i * 64 + lane], s);
    #pragma unroll
    for (int off = 32; off; off >>= 1) s += __shfl_xor(s, off);
    if (lane == 0) {
        float o = s + bd2[0] + 0.5f;
        out[n] = o;
        int g = graph_id[n];
        atomicAdd(&gsum[g], o);
        atomicAdd(&gcnt[g], 1.0f);
    }
}

__global__ void gdiv_kernel(const float* __restrict__ gsum,
                            const float* __restrict__ gcnt,
                            float* __restrict__ gout) {
    int g = blockIdx.x * blockDim.x + threadIdx.x;
    if (g < GG) gout[g] = gsum[g] / gcnt[g];
}

// ---------------------------------------------------------------------------
// launch
// ---------------------------------------------------------------------------
static inline size_t align_up(size_t x, size_t a) { return (x + a - 1) & ~(a - 1); }

extern "C" void kernel_launch(void* const* d_in, const int* in_sizes, int n_in,
                              void* d_out, int out_size, void* d_ws, size_t ws_size,
                              hipStream_t stream) {
    const int*   seq    = (const int*)d_in[0];
    const float* node_s = (const float*)d_in[1];
    const int*   src    = (const int*)d_in[2];
    const int*   dst    = (const int*)d_in[3];
    const int*   graph_id = (const int*)d_in[4];
    const float* W_emb  = (const float*)d_in[5];
    const float* W0     = (const float*)d_in[6];
    const float* al0    = (const float*)d_in[7];
    const float* ar0    = (const float*)d_in[8];
    const float* b0     = (const float*)d_in[9];
    const float* W1     = (const float*)d_in[10];
    const float* al1    = (const float*)d_in[11];
    const float* ar1    = (const float*)d_in[12];
    const float* b1     = (const float*)d_in[13];
    const float* W2     = (const float*)d_in[14];
    const float* al2    = (const float*)d_in[15];
    const float* ar2    = (const float*)d_in[16];
    const float* b2     = (const float*)d_in[17];
    const float* Wd1    = (const float*)d_in[18];
    const float* bd1    = (const float*)d_in[19];
    const float* Wd2    = (const float*)d_in[20];
    const float* bd2    = (const float*)d_in[21];

    float* out_nodes  = (float*)d_out;          // [N]
    float* out_graphs = (float*)d_out + NN;     // [G]

    // workspace carve-up
    char* p = (char*)d_ws;
    size_t off = 0;
    auto alloc = [&](size_t bytes) {
        void* r = p + off;
        off = align_up(off + bytes, 256);
        return r;
    };
    float* ftbuf  = (float*)alloc((size_t)NN * 512 * 4);  // ft / hidden
    float* hbuf   = (float*)alloc((size_t)NN * HD * 4);   // h between layers
    float* h0     = (float*)alloc((size_t)NN * NODE_IN * 4);
    float* el     = (float*)alloc((size_t)NN * HH * 4);
    float* er     = (float*)alloc((size_t)NN * HH * 4);
    int*   rowptr = (int*)alloc((size_t)(NN + 1) * 4);
    int*   fill   = (int*)alloc((size_t)NN * 4);          // also histogram counts
    int*   colsrc = (int*)alloc((size_t)EE * 4);
    float* gsum   = (float*)alloc(64 * 4);
    float* gcnt   = (float*)alloc(64 * 4);
    (void)ws_size;

    // ---- CSR build (dst-grouped), once per launch ----
    hipMemsetAsync(fill, 0, (size_t)NN * 4, stream);
    hist_kernel<<<1024, 256, 0, stream>>>(dst, fill);
    scan_kernel<<<1, 1024, 0, stream>>>(fill, rowptr);
    hipMemsetAsync(fill, 0, (size_t)NN * 4, stream);
    scatter_kernel<<<1024, 256, 0, stream>>>(src, dst, rowptr, fill, colsrc);

    // ---- embedding ----
    {
        int tot = NN * NODE_IN;
        embed_kernel<<<(tot + 255) / 256, 256, 0, stream>>>(seq, node_s, W_emb, h0, tot);
    }

    const int nodeWaves = (NN * 64 + 255) / 256;  // blocks of 4 waves
    dim3 g256(256 / 64, (NN + 63) / 64);
    dim3 g512(512 / 64, (NN + 63) / 64);

    // ---- layer 0 ----
    gemm_kernel<<<g256, 256, 0, stream>>>(h0, W0, ftbuf, nullptr, NN, HD, NODE_IN, 0);
    scores_kernel<<<nodeWaves, 256, 0, stream>>>(ftbuf, al0, ar0, el, er);
    aggregate_kernel<<<nodeWaves, 256, 0, stream>>>(ftbuf, el, er, rowptr, colsrc, b0, hbuf, 0);

    // ---- layer 1 ----
    gemm_kernel<<<g256, 256, 0, stream>>>(hbuf, W1, ftbuf, nullptr, NN, HD, HD, 0);
    scores_kernel<<<nodeWaves, 256, 0, stream>>>(ftbuf, al1, ar1, el, er);
    aggregate_kernel<<<nodeWaves, 256, 0, stream>>>(ftbuf, el, er, rowptr, colsrc, b1, hbuf, 0);

    // ---- layer 2 (relu fused into aggregate epilogue) ----
    gemm_kernel<<<g256, 256, 0, stream>>>(hbuf, W2, ftbuf, nullptr, NN, HD, HD, 0);
    scores_kernel<<<nodeWaves, 256, 0, stream>>>(ftbuf, al2, ar2, el, er);
    aggregate_kernel<<<nodeWaves, 256, 0, stream>>>(ftbuf, el, er, rowptr, colsrc, b2, hbuf, 1);

    // ---- dense head ----
    gemm_kernel<<<g512, 256, 0, stream>>>(hbuf, Wd1, ftbuf, bd1, NN, 512, HD, 1);
    hipMemsetAsync(gsum, 0, 64 * 4, stream);
    hipMemsetAsync(gcnt, 0, 64 * 4, stream);
    final_kernel<<<nodeWaves, 256, 0, stream>>>(ftbuf, Wd2, bd2, graph_id, out_nodes, gsum, gcnt);
    gdiv_kernel<<<1, 64, 0, stream>>>(gsum, gcnt, out_graphs);
}